// Round 6
// baseline (304.030 us; speedup 1.0000x reference)
//
#include <hip/hip_runtime.h>
#include <math.h>

#define BB 2
#define LL 2048
#define DIMM 1024
#define HH 16
#define DD 64
#define QKV_N 3072

typedef unsigned short u16;
typedef unsigned int u32;
typedef __attribute__((ext_vector_type(8))) short short8;   // 8 x bf16
typedef __attribute__((ext_vector_type(4))) float f32x4;
typedef __attribute__((ext_vector_type(16))) float f32x16;

__device__ __forceinline__ float bf2f(u16 h) {
    unsigned u = ((unsigned)h) << 16;
    return __uint_as_float(u);
}
__device__ __forceinline__ u16 f2bf(float f) {
    unsigned u = __float_as_uint(f);
    u += 0x7fffu + ((u >> 16) & 1u);   // round-to-nearest-even
    return (u16)(u >> 16);
}
// pack two f32 -> (bf16(hi)<<16)|bf16(lo), round-half-up
__device__ __forceinline__ u32 pack_bf2(float lo, float hi) {
    u32 a = __float_as_uint(hi) + 0x8000u;
    u32 b = __float_as_uint(lo) + 0x8000u;
    return __builtin_amdgcn_perm(a, b, 0x07060302u);
}
__device__ __forceinline__ f32x16 zero16() {
    f32x16 z;
#pragma unroll
    for (int i = 0; i < 16; ++i) z[i] = 0.f;
    return z;
}

// ---------------- f32 -> bf16 convert (x) -------------------------------------
__global__ __launch_bounds__(256) void convx(
    const float* __restrict__ X, u16* __restrict__ Xb)
{
    int i = (blockIdx.x * 256 + threadIdx.x) * 8;
    float4 a = *(const float4*)&X[i];
    float4 b = *(const float4*)&X[i + 4];
    u16 t[8] = {f2bf(a.x), f2bf(a.y), f2bf(a.z), f2bf(a.w),
                f2bf(b.x), f2bf(b.y), f2bf(b.z), f2bf(b.w)};
    *(uint4*)&Xb[i] = *(uint4*)t;
}

// ---------------- f32 [K,N] -> bf16 [N,K] transpose-convert -------------------
__global__ __launch_bounds__(256) void convt(
    const float* __restrict__ W, u16* __restrict__ Wt, int K, int N)
{
    __shared__ u16 s[64][72];
    const int tid = threadIdx.x;
    const int k0 = blockIdx.x * 64, n0 = blockIdx.y * 64;
#pragma unroll
    for (int t = 0; t < 16; ++t) {
        int flat = t * 256 + tid;
        int kk = flat >> 6, nn = flat & 63;
        s[nn][kk] = f2bf(W[(size_t)(k0 + kk) * N + n0 + nn]);
    }
    __syncthreads();
#pragma unroll
    for (int t = 0; t < 2; ++t) {
        int chunk = t * 256 + tid;
        int nn = chunk >> 3, kc = chunk & 7;
        *(uint4*)&Wt[(size_t)(n0 + nn) * K + k0 + kc * 8] = *(uint4*)&s[nn][kc * 8];
    }
}

// ---------------- bf16 v-slice -> vt[b,h,d,l] transpose -----------------------
__global__ __launch_bounds__(256) void vtrans(
    const u16* __restrict__ qkv, u16* __restrict__ vt)
{
    __shared__ u16 s[64][72];
    const int tid = threadIdx.x;
    const int bh = blockIdx.y;           // b*16 + h
    const int b = bh >> 4, h = bh & 15;
    const int l0 = blockIdx.x * 64;
    const u16* vbase = qkv + (size_t)b * LL * QKV_N + 2048 + h * 64;
#pragma unroll
    for (int t = 0; t < 2; ++t) {
        int flat = t * 2048 + tid * 8;
        int l = flat >> 6, d = flat & 63;
        *(uint4*)&s[l][d] = *(const uint4*)&vbase[(size_t)(l0 + l) * QKV_N + d];
    }
    __syncthreads();
#pragma unroll
    for (int t = 0; t < 2; ++t) {
        int flat = t * 2048 + tid * 8;
        int d = flat >> 6, l = flat & 63;
        u16 tmp[8];
#pragma unroll
        for (int j = 0; j < 8; ++j) tmp[j] = s[l + j][d];
        *(uint4*)&vt[((size_t)bh * 64 + d) * LL + l0 + l] = *(uint4*)tmp;
    }
}

// ---------------- QKV GEMM + fused RMSNorm/RoPE epilogue ----------------------
// C[4096,3072] = Xb[4096,1024] @ Wt[3072,1024]^T. q/k col-tiles get
// RMSNorm + RoPE applied on f32 accumulators before bf16 store.
__global__ __launch_bounds__(256) void gemm_qkv(
    const u16* __restrict__ A, const u16* __restrict__ Bt,
    u16* __restrict__ C, const float* __restrict__ pe,
    const float* __restrict__ qs, const float* __restrict__ ks)
{
    __shared__ u16 sA[128 * 72];
    __shared__ u16 sB[128 * 72];

    const int tid = threadIdx.x;
    const int wave = tid >> 6, lane = tid & 63;
    const int mIdx = lane & 15, quad = lane >> 4;
    const int wr = wave >> 1, wc = wave & 1;
    const int m0 = blockIdx.y * 128, n0 = blockIdx.x * 128;
    const int N = QKV_N, K = DIMM;

    f32x4 acc[4][4];
#pragma unroll
    for (int a = 0; a < 4; ++a)
#pragma unroll
        for (int b = 0; b < 4; ++b) acc[a][b] = (f32x4){0.f, 0.f, 0.f, 0.f};

    for (int k0 = 0; k0 < K; k0 += 64) {
#pragma unroll
        for (int t = 0; t < 4; ++t) {
            int ci = t * 256 + tid;
            int row = ci >> 3, kc = ci & 7;
            *(uint4*)&sA[row * 72 + kc * 8] =
                *(const uint4*)&A[(size_t)(m0 + row) * K + k0 + kc * 8];
            *(uint4*)&sB[row * 72 + kc * 8] =
                *(const uint4*)&Bt[(size_t)(n0 + row) * K + k0 + kc * 8];
        }
        __syncthreads();
#pragma unroll
        for (int ks2 = 0; ks2 < 2; ++ks2) {
            short8 af[4], bfr[4];
#pragma unroll
            for (int mt = 0; mt < 4; ++mt)
                af[mt] = *(const short8*)&sA[(64 * wr + 16 * mt + mIdx) * 72 + ks2 * 32 + quad * 8];
#pragma unroll
            for (int nt = 0; nt < 4; ++nt)
                bfr[nt] = *(const short8*)&sB[(64 * wc + 16 * nt + mIdx) * 72 + ks2 * 32 + quad * 8];
#pragma unroll
            for (int mt = 0; mt < 4; ++mt)
#pragma unroll
                for (int nt = 0; nt < 4; ++nt)
                    acc[mt][nt] = __builtin_amdgcn_mfma_f32_16x16x32_bf16(
                        af[mt], bfr[nt], acc[mt][nt], 0, 0, 0);
        }
        __syncthreads();
    }

    if (n0 >= 2048) {
        // v region: plain bf16 store
#pragma unroll
        for (int mt = 0; mt < 4; ++mt)
#pragma unroll
            for (int r = 0; r < 4; ++r) {
                int row = m0 + 64 * wr + 16 * mt + quad * 4 + r;
#pragma unroll
                for (int nt = 0; nt < 4; ++nt) {
                    int col = n0 + 64 * wc + 16 * nt + mIdx;
                    C[(size_t)row * N + col] = f2bf(acc[mt][nt][r]);
                }
            }
    } else {
        // q/k region: RMSNorm over head dim (the wave's 64 cols = one head)
        // + RoPE; q additionally prescaled by (1/8)*log2(e) for exp2 softmax.
        const float* scv = (n0 < 1024) ? qs : ks;
        const float pre = (n0 < 1024) ? 0.18033688011112042f : 1.0f;
        float scl[4];
#pragma unroll
        for (int nt = 0; nt < 4; ++nt) scl[nt] = scv[16 * nt + mIdx];

#pragma unroll
        for (int mt = 0; mt < 4; ++mt) {
#pragma unroll
            for (int r = 0; r < 4; ++r) {
                float s = 0.f;
#pragma unroll
                for (int nt = 0; nt < 4; ++nt) {
                    float a = acc[mt][nt][r];
                    s += a * a;
                }
                s += __shfl_xor(s, 1);
                s += __shfl_xor(s, 2);
                s += __shfl_xor(s, 4);
                s += __shfl_xor(s, 8);
                float rn = rsqrtf(s * (1.f / 64.f) + 1e-6f);
                int R = m0 + 64 * wr + 16 * mt + quad * 4 + r;   // = b*L + l
                size_t peo = (size_t)R * 128;
#pragma unroll
                for (int nt = 0; nt < 4; ++nt) {
                    float v = acc[mt][nt][r] * rn * scl[nt];
                    float pp = __shfl_xor(v, 1);
                    float2 pw = *(const float2*)&pe[peo + 2 * (16 * nt + mIdx)];
                    float e  = (mIdx & 1) ? pp : v;
                    float od = (mIdx & 1) ? v : pp;
                    C[(size_t)R * N + n0 + 64 * wc + 16 * nt + mIdx] =
                        f2bf((pw.x * e + pw.y * od) * pre);
                }
            }
        }
    }
}

// ---------------- proj GEMM (bf16 MFMA, f32 out + bias) -----------------------
__global__ __launch_bounds__(256) void gemm_proj(
    const u16* __restrict__ A, const u16* __restrict__ Bt,
    const float* __restrict__ bias, float* __restrict__ C)
{
    __shared__ u16 sA[128 * 72];
    __shared__ u16 sB[128 * 72];

    const int tid = threadIdx.x;
    const int wave = tid >> 6, lane = tid & 63;
    const int mIdx = lane & 15, quad = lane >> 4;
    const int wr = wave >> 1, wc = wave & 1;
    const int m0 = blockIdx.y * 128, n0 = blockIdx.x * 128;
    const int N = DIMM, K = DIMM;

    f32x4 acc[4][4];
#pragma unroll
    for (int a = 0; a < 4; ++a)
#pragma unroll
        for (int b = 0; b < 4; ++b) acc[a][b] = (f32x4){0.f, 0.f, 0.f, 0.f};

    for (int k0 = 0; k0 < K; k0 += 64) {
#pragma unroll
        for (int t = 0; t < 4; ++t) {
            int ci = t * 256 + tid;
            int row = ci >> 3, kc = ci & 7;
            *(uint4*)&sA[row * 72 + kc * 8] =
                *(const uint4*)&A[(size_t)(m0 + row) * K + k0 + kc * 8];
            *(uint4*)&sB[row * 72 + kc * 8] =
                *(const uint4*)&Bt[(size_t)(n0 + row) * K + k0 + kc * 8];
        }
        __syncthreads();
#pragma unroll
        for (int ks2 = 0; ks2 < 2; ++ks2) {
            short8 af[4], bfr[4];
#pragma unroll
            for (int mt = 0; mt < 4; ++mt)
                af[mt] = *(const short8*)&sA[(64 * wr + 16 * mt + mIdx) * 72 + ks2 * 32 + quad * 8];
#pragma unroll
            for (int nt = 0; nt < 4; ++nt)
                bfr[nt] = *(const short8*)&sB[(64 * wc + 16 * nt + mIdx) * 72 + ks2 * 32 + quad * 8];
#pragma unroll
            for (int mt = 0; mt < 4; ++mt)
#pragma unroll
                for (int nt = 0; nt < 4; ++nt)
                    acc[mt][nt] = __builtin_amdgcn_mfma_f32_16x16x32_bf16(
                        af[mt], bfr[nt], acc[mt][nt], 0, 0, 0);
        }
        __syncthreads();
    }

#pragma unroll
    for (int mt = 0; mt < 4; ++mt)
#pragma unroll
        for (int r = 0; r < 4; ++r) {
            int row = m0 + 64 * wr + 16 * mt + quad * 4 + r;
#pragma unroll
            for (int nt = 0; nt < 4; ++nt) {
                int col = n0 + 64 * wc + 16 * nt + mIdx;
                C[(size_t)row * N + col] = acc[mt][nt][r] + bias[col];
            }
        }
}

// ---------------- flash attention, 32x32x16 MFMA ------------------------------
// 512 thr = 8 waves, 32 q-rows/wave, 256 q-rows/block, grid = 256 (1/CU).
// S^T = mfma(A=K, B=Q^T): C col = q (lane&31) -> per-lane softmax sum, no
// shuffles; P written as 8 b64, read back as 4 b128 (wave-private rows).
// PV: O^T = mfma(A=V^T, B=P^T). Single-buffer K/V + register prefetch.
// LDS strides 70/66 keep every access <=2-way bank-aliased (free).
#define KPR 70
#define PPR 66

__global__ __launch_bounds__(512) void attn_mfma32(
    const u16* __restrict__ qkv, const u16* __restrict__ vt, u16* __restrict__ o)
{
    __shared__ u16 sK[64 * KPR];
    __shared__ u16 sVt[64 * KPR];
    __shared__ u16 sP[256 * PPR];   // reused for O transpose at the end

    const int tid = threadIdx.x;
    const int wave = tid >> 6;       // 0..7
    const int lane = tid & 63;
    const int m32 = lane & 31;
    const int half = lane >> 5;

    const int bh = blockIdx.x >> 3;  // 8 q-tiles of 256 rows per (b,h)
    const int qt = blockIdx.x & 7;
    const int b = bh >> 4, h = bh & 15;
    const int q0 = qt * 256;

    const u16* kbase = qkv + (size_t)b * LL * QKV_N + 1024 + h * 64;
    const u16* vbase = vt + (size_t)bh * 64 * LL;

    // Q B-frags (4 k-steps of 16 d each), straight from global
    const u16* qrow = qkv + ((size_t)(b * LL + q0 + 32 * wave + m32)) * QKV_N + h * 64;
    short8 qf[4];
#pragma unroll
    for (int s = 0; s < 4; ++s) qf[s] = *(const short8*)&qrow[16 * s + 8 * half];

    // staging: 512 threads cover one 64x64 tile (1 uint4 each for K and V)
    const int sr = tid >> 3, sc = (tid & 7) * 8;

    uint4 kreg = *(const uint4*)&kbase[(size_t)sr * QKV_N + sc];
    uint4 vreg = *(const uint4*)&vbase[(size_t)sr * LL + sc];

    float lsum = 0.f;
    f32x16 Oacc[2] = {zero16(), zero16()};

    u16* sProw = &sP[(32 * wave + m32) * PPR];

    for (int kt = 0; kt < 32; ++kt) {
        *(uint4*)&sK[sr * KPR + sc] = kreg;
        *(uint4*)&sVt[sr * KPR + sc] = vreg;
        __syncthreads();

        // register prefetch of tile kt+1 (latency hidden by compute below)
        if (kt + 1 < 32) {
            kreg = *(const uint4*)&kbase[(size_t)((kt + 1) * 64 + sr) * QKV_N + sc];
            vreg = *(const uint4*)&vbase[(size_t)sr * LL + (kt + 1) * 64 + sc];
        }

        // ---- S^T: 64 keys x 32 q ----
        f32x16 st[2] = {zero16(), zero16()};
#pragma unroll
        for (int s = 0; s < 4; ++s) {
#pragma unroll
            for (int mt = 0; mt < 2; ++mt) {
                short8 kf = *(const short8*)&sK[(32 * mt + m32) * KPR + 16 * s + 8 * half];
                st[mt] = __builtin_amdgcn_mfma_f32_32x32x16_bf16(kf, qf[s], st[mt], 0, 0, 0);
            }
        }

        // ---- softmax (exp2 domain, no running max), pack P to LDS ----
#pragma unroll
        for (int mt = 0; mt < 2; ++mt) {
            float p[16];
#pragma unroll
            for (int i = 0; i < 16; ++i) {
                p[i] = exp2f(st[mt][i]);
                lsum += p[i];
            }
#pragma unroll
            for (int g = 0; g < 4; ++g) {
                uint2 pr;
                pr.x = pack_bf2(p[4 * g + 0], p[4 * g + 1]);
                pr.y = pack_bf2(p[4 * g + 2], p[4 * g + 3]);
                // keys (reg&3)+8g+4half+32mt
                *(uint2*)&sProw[32 * mt + 4 * half + 8 * g] = pr;
            }
        }

        // ---- O^T += V^T @ P^T (sProw wave-private, no barrier needed) ----
#pragma unroll
        for (int s = 0; s < 4; ++s) {
            short8 pf = *(const short8*)&sProw[16 * s + 8 * half];
#pragma unroll
            for (int dt = 0; dt < 2; ++dt) {
                short8 vf = *(const short8*)&sVt[(32 * dt + m32) * KPR + 16 * s + 8 * half];
                Oacc[dt] = __builtin_amdgcn_mfma_f32_32x32x16_bf16(vf, pf, Oacc[dt], 0, 0, 0);
            }
        }
        __syncthreads();   // all waves done reading sK/sVt for tile kt
    }

    // final softmax denominator: other half of this q-row
    lsum += __shfl_xor(lsum, 32);
    float linv = 1.f / lsum;

    // write normalized O (bf16) into sP rows [q][d], then coalesced store
#pragma unroll
    for (int dt = 0; dt < 2; ++dt) {
#pragma unroll
        for (int g = 0; g < 4; ++g) {
            uint2 pr;
            pr.x = pack_bf2(Oacc[dt][4 * g + 0] * linv, Oacc[dt][4 * g + 1] * linv);
            pr.y = pack_bf2(Oacc[dt][4 * g + 2] * linv, Oacc[dt][4 * g + 3] * linv);
            *(uint2*)&sProw[32 * dt + 4 * half + 8 * g] = pr;
        }
    }
    __syncthreads();

    {
        const int row = tid >> 1, seg = tid & 1;   // 256 rows x 2 segments of 32 d
        size_t gbase = (size_t)(b * LL + q0 + row) * DIMM + h * 64 + 32 * seg;
#pragma unroll
        for (int c = 0; c < 4; ++c) {
            uint4 v = *(const uint4*)&sP[row * PPR + 32 * seg + 8 * c];
            *(uint4*)&o[gbase + 8 * c] = v;
        }
    }
}

extern "C" void kernel_launch(void* const* d_in, const int* in_sizes, int n_in,
                              void* d_out, int out_size, void* d_ws, size_t ws_size,
                              hipStream_t stream) {
    const float* x       = (const float*)d_in[0];
    const float* pe      = (const float*)d_in[1];
    const float* w_qkv   = (const float*)d_in[2];
    const float* q_scale = (const float*)d_in[3];
    const float* k_scale = (const float*)d_in[4];
    const float* w_proj  = (const float*)d_in[5];
    const float* b_proj  = (const float*)d_in[6];
    float* out = (float*)d_out;

    char* ws = (char*)d_ws;
    u16* qkv    = (u16*)ws;  ws += (size_t)4096 * 3072 * 2;
    u16* o      = (u16*)ws;  ws += (size_t)4096 * 1024 * 2;
    u16* xb     = (u16*)ws;  ws += (size_t)4096 * 1024 * 2;
    u16* wqkvt  = (u16*)ws;  ws += (size_t)3072 * 1024 * 2;
    u16* wprojt = (u16*)ws;  ws += (size_t)1024 * 1024 * 2;
    u16* vtbuf  = (u16*)ws;  ws += (size_t)BB * HH * DD * LL * 2;

    // 0. conversions
    convx<<<(4096 * 1024) / (256 * 8), 256, 0, stream>>>(x, xb);
    convt<<<dim3(1024 / 64, QKV_N / 64), 256, 0, stream>>>(w_qkv, wqkvt, DIMM, QKV_N);
    convt<<<dim3(1024 / 64, 1024 / 64), 256, 0, stream>>>(w_proj, wprojt, DIMM, DIMM);

    // 1. fused QKV projection + RMSNorm + RoPE epilogue
    gemm_qkv<<<dim3(QKV_N / 128, (BB * LL) / 128), 256, 0, stream>>>(
        xb, wqkvt, qkv, pe, q_scale, k_scale);

    // 2. V transpose -> vt[b,h,d,l]
    vtrans<<<dim3(LL / 64, BB * HH), 256, 0, stream>>>(qkv, vtbuf);

    // 3. attention (32x32x16 MFMA)
    attn_mfma32<<<BB * HH * (LL / 256), 512, 0, stream>>>(qkv, vtbuf, o);

    // 4. output projection + bias (f32 out)
    gemm_proj<<<dim3(DIMM / 128, (BB * LL) / 128), 256, 0, stream>>>(
        o, wprojt, b_proj, out);
}